// Round 1
// baseline (4414.742 us; speedup 1.0000x reference)
//
#include <hip/hip_runtime.h>

// GraphConv x3: out_i = W_rel @ sum_{j->i} hd_j + W_root @ hd_i + b, hd = dropout(h)
// N=50000, E=800000, C=128 throughout. fp32 everywhere this round.

#define C128 128

// ---------------------------------------------------------------------------
// Detect on device (graph capture forbids host-side data inspection):
// flags[0] = 1 if edge_index buffer is int64-layout, 0 if int32
// flags[1] = 1 if dropout masks are int32-layout, 0 if uint8 (numpy bool)
// ---------------------------------------------------------------------------
__global__ __launch_bounds__(64) void detect_kernel(const int* __restrict__ eidx,
                                                    const int* __restrict__ mask,
                                                    int* __restrict__ flags) {
  if (threadIdx.x == 0) {
    int e64 = 1;
    for (int i = 0; i < 64; ++i) {
      if (eidx[2 * i + 1] != 0) { e64 = 0; break; }
    }
    int m32 = 1;
    for (int i = 0; i < 64; ++i) {
      unsigned v = (unsigned)mask[i];
      if (v > 1u) { m32 = 0; break; }
    }
    flags[0] = e64;
    flags[1] = m32;
  }
}

// ---------------------------------------------------------------------------
// Dropout: hd = keep ? x * 2.5 : 0   (4 elements / thread, float4)
// ---------------------------------------------------------------------------
__global__ __launch_bounds__(256) void dropout_kernel(const float* __restrict__ x,
                                                      const void* __restrict__ mask,
                                                      const int* __restrict__ flags,
                                                      float* __restrict__ out, int n4) {
  int i = blockIdx.x * 256 + threadIdx.x;
  if (i >= n4) return;
  float4 v = ((const float4*)x)[i];
  int k0, k1, k2, k3;
  if (flags[1]) {
    int4 m = ((const int4*)mask)[i];
    k0 = m.x; k1 = m.y; k2 = m.z; k3 = m.w;
  } else {
    uchar4 m = ((const uchar4*)mask)[i];
    k0 = m.x; k1 = m.y; k2 = m.z; k3 = m.w;
  }
  float4 r;
  r.x = k0 ? v.x * 2.5f : 0.f;
  r.y = k1 ? v.y * 2.5f : 0.f;
  r.z = k2 ? v.z * 2.5f : 0.f;
  r.w = k3 ? v.w * 2.5f : 0.f;
  ((float4*)out)[i] = r;
}

// ---------------------------------------------------------------------------
// Edge scatter: agg[dst] += hd[src], 32 threads/edge, 4 channels each (float4
// read, 4 fp32 atomics). Expected hot spot this round.
// ---------------------------------------------------------------------------
__global__ __launch_bounds__(256) void scatter_kernel(const float* __restrict__ hd,
                                                      const int* __restrict__ eidx,
                                                      const int* __restrict__ flags,
                                                      float* __restrict__ agg, int E) {
  int gid = blockIdx.x * 256 + threadIdx.x;
  int e = gid >> 5;
  if (e >= E) return;
  int c = (gid & 31) * 4;
  int src, dst;
  if (flags[0]) {                 // int64 layout: low words at stride 2
    src = eidx[2 * e];
    dst = eidx[2 * E + 2 * e];
  } else {                        // int32 layout
    src = eidx[e];
    dst = eidx[E + e];
  }
  float4 v = *(const float4*)&hd[src * C128 + c];
  float* d = &agg[dst * C128 + c];
  atomicAdd(d + 0, v.x);
  atomicAdd(d + 1, v.y);
  atomicAdd(d + 2, v.z);
  atomicAdd(d + 3, v.w);
}

// ---------------------------------------------------------------------------
// Fused dual GEMM: out[i,o] = sum_k agg[i,k]*Wrel[o,k] + sum_k hd[i,k]*Wroot[o,k]
//                  + b[o], optional ReLU.
// Tile: 32 nodes x 128 outs per block (256 threads, 4x4 per thread).
// K looped in 8 chunks of 32 (chunks 0-3: agg/Wrel, 4-7: hd/Wroot).
// LDS stored k-major so the inner loop does 2x ds_read_b128 per 16 FMA.
// ---------------------------------------------------------------------------
__global__ __launch_bounds__(256) void gemm_kernel(const float* __restrict__ agg,
                                                   const float* __restrict__ hd,
                                                   const float* __restrict__ Wrel,
                                                   const float* __restrict__ Wroot,
                                                   const float* __restrict__ bias,
                                                   float* __restrict__ out,
                                                   int relu, int N) {
  __shared__ float As[32][36];    // [k][node], padded
  __shared__ float Wsm[32][132];  // [k][out], padded

  const int tid = threadIdx.x;
  const int node0 = blockIdx.x * 32;
  const int o_base = (tid & 31) * 4;
  const int n_base = (tid >> 5) * 4;

  float acc[4][4] = {{0.f}};

  for (int chunk = 0; chunk < 8; ++chunk) {
    const float* A = (chunk < 4) ? agg : hd;
    const float* W = (chunk < 4) ? Wrel : Wroot;
    const int k0 = (chunk & 3) * 32;

    // Stage A chunk: 32 nodes x 32 k. 4 floats/thread.
    {
      int node = tid >> 3;
      int kk = (tid & 7) * 4;
      int gnode = node0 + node;
      if (gnode > N - 1) gnode = N - 1;
      float4 v = *(const float4*)&A[gnode * C128 + k0 + kk];
      As[kk + 0][node] = v.x;
      As[kk + 1][node] = v.y;
      As[kk + 2][node] = v.z;
      As[kk + 3][node] = v.w;
    }
    // Stage W chunk: 128 out x 32 k. 16 floats/thread.
#pragma unroll
    for (int r = 0; r < 4; ++r) {
      int t = tid + r * 256;
      int o = t >> 3;
      int kk = (t & 7) * 4;
      float4 v = *(const float4*)&W[o * C128 + k0 + kk];
      Wsm[kk + 0][o] = v.x;
      Wsm[kk + 1][o] = v.y;
      Wsm[kk + 2][o] = v.z;
      Wsm[kk + 3][o] = v.w;
    }
    __syncthreads();

#pragma unroll
    for (int k = 0; k < 32; ++k) {
      float4 a4 = *(const float4*)&As[k][n_base];
      float4 w4 = *(const float4*)&Wsm[k][o_base];
      float av[4] = {a4.x, a4.y, a4.z, a4.w};
      float wv[4] = {w4.x, w4.y, w4.z, w4.w};
#pragma unroll
      for (int i = 0; i < 4; ++i)
#pragma unroll
        for (int j = 0; j < 4; ++j) acc[i][j] += av[i] * wv[j];
    }
    __syncthreads();
  }

#pragma unroll
  for (int i = 0; i < 4; ++i) {
    int node = node0 + n_base + i;
    if (node >= N) continue;
#pragma unroll
    for (int j = 0; j < 4; ++j) {
      float v = acc[i][j] + bias[o_base + j];
      if (relu) v = fmaxf(v, 0.f);
      out[node * C128 + o_base + j] = v;
    }
  }
}

// ---------------------------------------------------------------------------
extern "C" void kernel_launch(void* const* d_in, const int* in_sizes, int n_in,
                              void* d_out, int out_size, void* d_ws, size_t ws_size,
                              hipStream_t stream) {
  const float* x      = (const float*)d_in[0];
  const int*   eidx   = (const int*)d_in[1];
  const float* Wrel0  = (const float*)d_in[2];
  const float* Wroot0 = (const float*)d_in[3];
  const float* b0     = (const float*)d_in[4];
  const float* Wrel1  = (const float*)d_in[5];
  const float* Wroot1 = (const float*)d_in[6];
  const float* b1     = (const float*)d_in[7];
  const float* Wrel2  = (const float*)d_in[8];
  const float* Wroot2 = (const float*)d_in[9];
  const float* b2     = (const float*)d_in[10];
  const void*  drop0  = d_in[11];
  const void*  drop1  = d_in[12];
  const void*  drop2  = d_in[13];

  const int N  = in_sizes[0] / C128;
  const int E  = in_sizes[1] / 2;   // flat element count is 2*E for either dtype
  const int NC = N * C128;

  char*  ws    = (char*)d_ws;
  int*   flags = (int*)ws;
  float* hd    = (float*)(ws + 256);
  float* agg   = hd + NC;
  float* h1    = agg + NC;

  detect_kernel<<<1, 64, 0, stream>>>(eidx, (const int*)drop0, flags);

  const int n4 = NC / 4;
  const int dropGrid = (n4 + 255) / 256;
  const int scatGrid = (E * 32 + 255) / 256;
  const int gemmGrid = (N + 31) / 32;

  // ---- layer 0 ----
  dropout_kernel<<<dropGrid, 256, 0, stream>>>(x, drop0, flags, hd, n4);
  hipMemsetAsync(agg, 0, (size_t)NC * sizeof(float), stream);
  scatter_kernel<<<scatGrid, 256, 0, stream>>>(hd, eidx, flags, agg, E);
  gemm_kernel<<<gemmGrid, 256, 0, stream>>>(agg, hd, Wrel0, Wroot0, b0, h1, 1, N);

  // ---- layer 1 ----
  dropout_kernel<<<dropGrid, 256, 0, stream>>>(h1, drop1, flags, hd, n4);
  hipMemsetAsync(agg, 0, (size_t)NC * sizeof(float), stream);
  scatter_kernel<<<scatGrid, 256, 0, stream>>>(hd, eidx, flags, agg, E);
  gemm_kernel<<<gemmGrid, 256, 0, stream>>>(agg, hd, Wrel1, Wroot1, b1, h1, 1, N);

  // ---- layer 2 (no relu, write d_out) ----
  dropout_kernel<<<dropGrid, 256, 0, stream>>>(h1, drop2, flags, hd, n4);
  hipMemsetAsync(agg, 0, (size_t)NC * sizeof(float), stream);
  scatter_kernel<<<scatGrid, 256, 0, stream>>>(hd, eidx, flags, agg, E);
  gemm_kernel<<<gemmGrid, 256, 0, stream>>>(agg, hd, Wrel2, Wroot2, b2,
                                            (float*)d_out, 0, N);
}

// Round 2
// 613.120 us; speedup vs baseline: 7.2005x; 7.2005x over previous
//
#include <hip/hip_runtime.h>

// GraphConv x3: out_i = W_rel @ sum_{j->i} hd_j + W_root @ hd_i + b, hd = dropout(h)
// N=50000, E=800000, C=128.
// R2: replace fp32 atomic scatter (1355us/layer, WRITE_SIZE=1.6GB of coherent
// atomic RMW traffic) with on-device CSR build + gather aggregation.

#define C128 128

// ---------------------------------------------------------------------------
// flags[0]=1 if edge_index is int64-layout; flags[1]=1 if masks are int32.
// ---------------------------------------------------------------------------
__global__ __launch_bounds__(64) void detect_kernel(const int* __restrict__ eidx,
                                                    const int* __restrict__ mask,
                                                    int* __restrict__ flags) {
  if (threadIdx.x == 0) {
    int e64 = 1;
    for (int i = 0; i < 64; ++i)
      if (eidx[2 * i + 1] != 0) { e64 = 0; break; }
    int m32 = 1;
    for (int i = 0; i < 64; ++i)
      if ((unsigned)mask[i] > 1u) { m32 = 0; break; }
    flags[0] = e64;
    flags[1] = m32;
  }
}

// ---------------------------------------------------------------------------
// CSR build: histogram of dst -> exclusive scan -> slot scatter of src ids.
// Int atomics on L2-resident 200KB array; cheap.
// ---------------------------------------------------------------------------
__global__ __launch_bounds__(256) void hist_kernel(const int* __restrict__ eidx,
                                                   const int* __restrict__ flags,
                                                   int* __restrict__ deg, int E) {
  int e = blockIdx.x * 256 + threadIdx.x;
  if (e >= E) return;
  int dst = flags[0] ? eidx[2 * E + 2 * e] : eidx[E + e];
  atomicAdd(&deg[dst], 1);
}

__global__ __launch_bounds__(256) void scan1_kernel(const int* __restrict__ deg,
                                                    int* __restrict__ blockSums, int N) {
  __shared__ int s[256];
  int i = blockIdx.x * 256 + threadIdx.x;
  s[threadIdx.x] = (i < N) ? deg[i] : 0;
  __syncthreads();
  for (int off = 128; off > 0; off >>= 1) {
    if (threadIdx.x < off) s[threadIdx.x] += s[threadIdx.x + off];
    __syncthreads();
  }
  if (threadIdx.x == 0) blockSums[blockIdx.x] = s[0];
}

__global__ __launch_bounds__(64) void scan2_kernel(int* __restrict__ blockSums, int nb) {
  if (threadIdx.x == 0) {
    int acc = 0;
    for (int i = 0; i < nb; ++i) { int v = blockSums[i]; blockSums[i] = acc; acc += v; }
  }
}

__global__ __launch_bounds__(256) void scan3_kernel(const int* __restrict__ deg,
                                                    const int* __restrict__ blockSums,
                                                    int* __restrict__ rowPtr,
                                                    int* __restrict__ cur, int N) {
  __shared__ int s[256];
  int i = blockIdx.x * 256 + threadIdx.x;
  int v = (i < N) ? deg[i] : 0;
  s[threadIdx.x] = v;
  __syncthreads();
  for (int off = 1; off < 256; off <<= 1) {
    int t = (threadIdx.x >= (unsigned)off) ? s[threadIdx.x - off] : 0;
    __syncthreads();
    s[threadIdx.x] += t;
    __syncthreads();
  }
  int excl = s[threadIdx.x] - v + blockSums[blockIdx.x];
  if (i < N) {
    rowPtr[i] = excl;
    cur[i] = excl;
    if (i == N - 1) rowPtr[N] = excl + v;
  }
}

__global__ __launch_bounds__(256) void fill_kernel(const int* __restrict__ eidx,
                                                   const int* __restrict__ flags,
                                                   int* __restrict__ cur,
                                                   int* __restrict__ csrSrc, int E) {
  int e = blockIdx.x * 256 + threadIdx.x;
  if (e >= E) return;
  int src, dst;
  if (flags[0]) { src = eidx[2 * e]; dst = eidx[2 * E + 2 * e]; }
  else          { src = eidx[e];     dst = eidx[E + e]; }
  int pos = atomicAdd(&cur[dst], 1);
  csrSrc[pos] = src;
}

// ---------------------------------------------------------------------------
// Dropout: hd = keep ? x * 2.5 : 0
// ---------------------------------------------------------------------------
__global__ __launch_bounds__(256) void dropout_kernel(const float* __restrict__ x,
                                                      const void* __restrict__ mask,
                                                      const int* __restrict__ flags,
                                                      float* __restrict__ out, int n4) {
  int i = blockIdx.x * 256 + threadIdx.x;
  if (i >= n4) return;
  float4 v = ((const float4*)x)[i];
  int k0, k1, k2, k3;
  if (flags[1]) {
    int4 m = ((const int4*)mask)[i];
    k0 = m.x; k1 = m.y; k2 = m.z; k3 = m.w;
  } else {
    uchar4 m = ((const uchar4*)mask)[i];
    k0 = m.x; k1 = m.y; k2 = m.z; k3 = m.w;
  }
  float4 r;
  r.x = k0 ? v.x * 2.5f : 0.f;
  r.y = k1 ? v.y * 2.5f : 0.f;
  r.z = k2 ? v.z * 2.5f : 0.f;
  r.w = k3 ? v.w * 2.5f : 0.f;
  ((float4*)out)[i] = r;
}

// ---------------------------------------------------------------------------
// Gather aggregation: one wave per dst node; lane handles 2 channels (float2).
// Unroll-2 over edges for 2 loads in flight. No atomics; agg written once.
// ---------------------------------------------------------------------------
__global__ __launch_bounds__(256) void gather_kernel(const float* __restrict__ hd,
                                                     const int* __restrict__ rowPtr,
                                                     const int* __restrict__ csrSrc,
                                                     float* __restrict__ agg, int N) {
  int wave = (blockIdx.x * 256 + threadIdx.x) >> 6;
  if (wave >= N) return;
  int lane = threadIdx.x & 63;
  int c = lane * 2;
  int beg = __builtin_amdgcn_readfirstlane(rowPtr[wave]);
  int end = __builtin_amdgcn_readfirstlane(rowPtr[wave + 1]);
  float ax = 0.f, ay = 0.f, bx = 0.f, by = 0.f;
  int e = beg;
  for (; e + 1 < end; e += 2) {
    int s0 = __builtin_amdgcn_readfirstlane(csrSrc[e]);
    int s1 = __builtin_amdgcn_readfirstlane(csrSrc[e + 1]);
    float2 v0 = *(const float2*)&hd[(size_t)s0 * C128 + c];
    float2 v1 = *(const float2*)&hd[(size_t)s1 * C128 + c];
    ax += v0.x; ay += v0.y;
    bx += v1.x; by += v1.y;
  }
  if (e < end) {
    int s0 = __builtin_amdgcn_readfirstlane(csrSrc[e]);
    float2 v0 = *(const float2*)&hd[(size_t)s0 * C128 + c];
    ax += v0.x; ay += v0.y;
  }
  float2 r; r.x = ax + bx; r.y = ay + by;
  *(float2*)&agg[(size_t)wave * C128 + c] = r;
}

// ---------------------------------------------------------------------------
// Fused dual GEMM: out[i,o] = agg[i,:]·Wrel[o,:] + hd[i,:]·Wroot[o,:] + b[o]
// 32 nodes x 128 outs per block (256 threads, 4x4/thread).
// ---------------------------------------------------------------------------
__global__ __launch_bounds__(256) void gemm_kernel(const float* __restrict__ agg,
                                                   const float* __restrict__ hd,
                                                   const float* __restrict__ Wrel,
                                                   const float* __restrict__ Wroot,
                                                   const float* __restrict__ bias,
                                                   float* __restrict__ out,
                                                   int relu, int N) {
  __shared__ float As[32][36];
  __shared__ float Wsm[32][132];

  const int tid = threadIdx.x;
  const int node0 = blockIdx.x * 32;
  const int o_base = (tid & 31) * 4;
  const int n_base = (tid >> 5) * 4;

  float acc[4][4] = {{0.f}};

  for (int chunk = 0; chunk < 8; ++chunk) {
    const float* A = (chunk < 4) ? agg : hd;
    const float* W = (chunk < 4) ? Wrel : Wroot;
    const int k0 = (chunk & 3) * 32;

    {
      int node = tid >> 3;
      int kk = (tid & 7) * 4;
      int gnode = node0 + node;
      if (gnode > N - 1) gnode = N - 1;
      float4 v = *(const float4*)&A[gnode * C128 + k0 + kk];
      As[kk + 0][node] = v.x;
      As[kk + 1][node] = v.y;
      As[kk + 2][node] = v.z;
      As[kk + 3][node] = v.w;
    }
#pragma unroll
    for (int r = 0; r < 4; ++r) {
      int t = tid + r * 256;
      int o = t >> 3;
      int kk = (t & 7) * 4;
      float4 v = *(const float4*)&W[o * C128 + k0 + kk];
      Wsm[kk + 0][o] = v.x;
      Wsm[kk + 1][o] = v.y;
      Wsm[kk + 2][o] = v.z;
      Wsm[kk + 3][o] = v.w;
    }
    __syncthreads();

#pragma unroll
    for (int k = 0; k < 32; ++k) {
      float4 a4 = *(const float4*)&As[k][n_base];
      float4 w4 = *(const float4*)&Wsm[k][o_base];
      float av[4] = {a4.x, a4.y, a4.z, a4.w};
      float wv[4] = {w4.x, w4.y, w4.z, w4.w};
#pragma unroll
      for (int i = 0; i < 4; ++i)
#pragma unroll
        for (int j = 0; j < 4; ++j) acc[i][j] += av[i] * wv[j];
    }
    __syncthreads();
  }

#pragma unroll
  for (int i = 0; i < 4; ++i) {
    int node = node0 + n_base + i;
    if (node >= N) continue;
#pragma unroll
    for (int j = 0; j < 4; ++j) {
      float v = acc[i][j] + bias[o_base + j];
      if (relu) v = fmaxf(v, 0.f);
      out[node * C128 + o_base + j] = v;
    }
  }
}

// ---------------------------------------------------------------------------
extern "C" void kernel_launch(void* const* d_in, const int* in_sizes, int n_in,
                              void* d_out, int out_size, void* d_ws, size_t ws_size,
                              hipStream_t stream) {
  const float* x      = (const float*)d_in[0];
  const int*   eidx   = (const int*)d_in[1];
  const float* Wrel0  = (const float*)d_in[2];
  const float* Wroot0 = (const float*)d_in[3];
  const float* b0     = (const float*)d_in[4];
  const float* Wrel1  = (const float*)d_in[5];
  const float* Wroot1 = (const float*)d_in[6];
  const float* b1     = (const float*)d_in[7];
  const float* Wrel2  = (const float*)d_in[8];
  const float* Wroot2 = (const float*)d_in[9];
  const float* b2     = (const float*)d_in[10];
  const void*  drop0  = d_in[11];
  const void*  drop1  = d_in[12];
  const void*  drop2  = d_in[13];

  const int N  = in_sizes[0] / C128;
  const int E  = in_sizes[1] / 2;
  const int NC = N * C128;
  const int nb = (N + 255) / 256;

  char*  ws      = (char*)d_ws;
  int*   flags   = (int*)ws;                       // 256 B
  float* hd      = (float*)(ws + 256);
  float* agg     = hd + NC;
  float* h1      = agg + NC;
  int*   deg     = (int*)(h1 + NC);                // N
  int*   rowPtr  = deg + N;                        // N+1
  int*   cur     = rowPtr + N + 1;                 // N
  int*   csrSrc  = cur + N;                        // E
  int*   bsums   = csrSrc + E;                     // nb (<=256)

  detect_kernel<<<1, 64, 0, stream>>>(eidx, (const int*)drop0, flags);

  // ---- CSR build (once; reused by all 3 layers) ----
  hipMemsetAsync(deg, 0, (size_t)N * sizeof(int), stream);
  hist_kernel<<<(E + 255) / 256, 256, 0, stream>>>(eidx, flags, deg, E);
  scan1_kernel<<<nb, 256, 0, stream>>>(deg, bsums, N);
  scan2_kernel<<<1, 64, 0, stream>>>(bsums, nb);
  scan3_kernel<<<nb, 256, 0, stream>>>(deg, bsums, rowPtr, cur, N);
  fill_kernel<<<(E + 255) / 256, 256, 0, stream>>>(eidx, flags, cur, csrSrc, E);

  const int n4 = NC / 4;
  const int dropGrid = (n4 + 255) / 256;
  const int gathGrid = (N + 3) / 4;     // one wave per node, 4 waves/block
  const int gemmGrid = (N + 31) / 32;

  // ---- layer 0 ----
  dropout_kernel<<<dropGrid, 256, 0, stream>>>(x, drop0, flags, hd, n4);
  gather_kernel<<<gathGrid, 256, 0, stream>>>(hd, rowPtr, csrSrc, agg, N);
  gemm_kernel<<<gemmGrid, 256, 0, stream>>>(agg, hd, Wrel0, Wroot0, b0, h1, 1, N);

  // ---- layer 1 ----
  dropout_kernel<<<dropGrid, 256, 0, stream>>>(h1, drop1, flags, hd, n4);
  gather_kernel<<<gathGrid, 256, 0, stream>>>(hd, rowPtr, csrSrc, agg, N);
  gemm_kernel<<<gemmGrid, 256, 0, stream>>>(agg, hd, Wrel1, Wroot1, b1, h1, 1, N);

  // ---- layer 2 (no relu, write d_out) ----
  dropout_kernel<<<dropGrid, 256, 0, stream>>>(h1, drop2, flags, hd, n4);
  gather_kernel<<<gathGrid, 256, 0, stream>>>(hd, rowPtr, csrSrc, agg, N);
  gemm_kernel<<<gemmGrid, 256, 0, stream>>>(agg, hd, Wrel2, Wroot2, b2,
                                            (float*)d_out, 0, N);
}

// Round 3
// 476.258 us; speedup vs baseline: 9.2696x; 1.2874x over previous
//
#include <hip/hip_runtime.h>

// GraphConv x3 on MI355X. R3: bf16 internal features/weights + MFMA GEMM
// (16x16x32 bf16), bf16 gather (halved L2 traffic), ReLU+dropout fused into
// GEMM epilogue. fp32 accumulation everywhere.

#define C128 128

typedef short s16x8 __attribute__((ext_vector_type(8)));
typedef float f32x4 __attribute__((ext_vector_type(4)));

__device__ __forceinline__ ushort f2bf(float f) {        // RNE fp32->bf16
  unsigned u = __builtin_bit_cast(unsigned, f);
  u = (u + 0x7FFFu + ((u >> 16) & 1u)) >> 16;
  return (ushort)u;
}
__device__ __forceinline__ float bflo(unsigned v) {      // low ushort -> f32
  return __builtin_bit_cast(float, v << 16);
}
__device__ __forceinline__ float bfhi(unsigned v) {      // high ushort -> f32
  return __builtin_bit_cast(float, v & 0xFFFF0000u);
}

// ---------------------------------------------------------------------------
// flags[0]=1 if edge_index is int64-layout; flags[1]=1 if masks are int32.
// ---------------------------------------------------------------------------
__global__ __launch_bounds__(64) void detect_kernel(const int* __restrict__ eidx,
                                                    const int* __restrict__ mask,
                                                    int* __restrict__ flags) {
  if (threadIdx.x == 0) {
    int e64 = 1;
    for (int i = 0; i < 64; ++i)
      if (eidx[2 * i + 1] != 0) { e64 = 0; break; }
    int m32 = 1;
    for (int i = 0; i < 64; ++i)
      if ((unsigned)mask[i] > 1u) { m32 = 0; break; }
    flags[0] = e64;
    flags[1] = m32;
  }
}

// ---------------------------------------------------------------------------
// Convert 6 weight matrices (128x128 fp32) to bf16, concatenated.
// ---------------------------------------------------------------------------
__global__ __launch_bounds__(256) void wconv_kernel(const float* __restrict__ s0,
                                                    const float* __restrict__ s1,
                                                    const float* __restrict__ s2,
                                                    const float* __restrict__ s3,
                                                    const float* __restrict__ s4,
                                                    const float* __restrict__ s5,
                                                    ushort* __restrict__ dst) {
  int i = blockIdx.x * 256 + threadIdx.x;
  if (i >= 6 * 16384) return;
  int m = i >> 14, r = i & 16383;
  const float* s = (m == 0) ? s0 : (m == 1) ? s1 : (m == 2) ? s2
                  : (m == 3) ? s3 : (m == 4) ? s4 : s5;
  dst[i] = f2bf(s[r]);
}

// ---------------------------------------------------------------------------
// CSR build (unchanged from R2; int atomics on L2-resident arrays).
// ---------------------------------------------------------------------------
__global__ __launch_bounds__(256) void hist_kernel(const int* __restrict__ eidx,
                                                   const int* __restrict__ flags,
                                                   int* __restrict__ deg, int E) {
  int e = blockIdx.x * 256 + threadIdx.x;
  if (e >= E) return;
  int dst = flags[0] ? eidx[2 * E + 2 * e] : eidx[E + e];
  atomicAdd(&deg[dst], 1);
}

__global__ __launch_bounds__(256) void scan1_kernel(const int* __restrict__ deg,
                                                    int* __restrict__ blockSums, int N) {
  __shared__ int s[256];
  int i = blockIdx.x * 256 + threadIdx.x;
  s[threadIdx.x] = (i < N) ? deg[i] : 0;
  __syncthreads();
  for (int off = 128; off > 0; off >>= 1) {
    if (threadIdx.x < off) s[threadIdx.x] += s[threadIdx.x + off];
    __syncthreads();
  }
  if (threadIdx.x == 0) blockSums[blockIdx.x] = s[0];
}

__global__ __launch_bounds__(64) void scan2_kernel(int* __restrict__ blockSums, int nb) {
  if (threadIdx.x == 0) {
    int acc = 0;
    for (int i = 0; i < nb; ++i) { int v = blockSums[i]; blockSums[i] = acc; acc += v; }
  }
}

__global__ __launch_bounds__(256) void scan3_kernel(const int* __restrict__ deg,
                                                    const int* __restrict__ blockSums,
                                                    int* __restrict__ rowPtr,
                                                    int* __restrict__ cur, int N) {
  __shared__ int s[256];
  int i = blockIdx.x * 256 + threadIdx.x;
  int v = (i < N) ? deg[i] : 0;
  s[threadIdx.x] = v;
  __syncthreads();
  for (int off = 1; off < 256; off <<= 1) {
    int t = (threadIdx.x >= (unsigned)off) ? s[threadIdx.x - off] : 0;
    __syncthreads();
    s[threadIdx.x] += t;
    __syncthreads();
  }
  int excl = s[threadIdx.x] - v + blockSums[blockIdx.x];
  if (i < N) {
    rowPtr[i] = excl;
    cur[i] = excl;
    if (i == N - 1) rowPtr[N] = excl + v;
  }
}

__global__ __launch_bounds__(256) void fill_kernel(const int* __restrict__ eidx,
                                                   const int* __restrict__ flags,
                                                   int* __restrict__ cur,
                                                   int* __restrict__ csrSrc, int E) {
  int e = blockIdx.x * 256 + threadIdx.x;
  if (e >= E) return;
  int src, dst;
  if (flags[0]) { src = eidx[2 * e]; dst = eidx[2 * E + 2 * e]; }
  else          { src = eidx[e];     dst = eidx[E + e]; }
  int pos = atomicAdd(&cur[dst], 1);
  csrSrc[pos] = src;
}

// ---------------------------------------------------------------------------
// Input dropout: fp32 x -> bf16 hd, keep ? x*2.5 : 0. 4 elems/thread.
// ---------------------------------------------------------------------------
__global__ __launch_bounds__(256) void drop_in_kernel(const float* __restrict__ x,
                                                      const void* __restrict__ mask,
                                                      const int* __restrict__ flags,
                                                      ushort* __restrict__ out, int n4) {
  int i = blockIdx.x * 256 + threadIdx.x;
  if (i >= n4) return;
  float4 v = ((const float4*)x)[i];
  int k0, k1, k2, k3;
  if (flags[1]) {
    int4 m = ((const int4*)mask)[i];
    k0 = m.x; k1 = m.y; k2 = m.z; k3 = m.w;
  } else {
    uchar4 m = ((const uchar4*)mask)[i];
    k0 = m.x; k1 = m.y; k2 = m.z; k3 = m.w;
  }
  ushort4 r;
  r.x = k0 ? f2bf(v.x * 2.5f) : (ushort)0;
  r.y = k1 ? f2bf(v.y * 2.5f) : (ushort)0;
  r.z = k2 ? f2bf(v.z * 2.5f) : (ushort)0;
  r.w = k3 ? f2bf(v.w * 2.5f) : (ushort)0;
  ((ushort4*)out)[i] = r;
}

// ---------------------------------------------------------------------------
// Gather aggregation (bf16): one wave per dst node, lane = 2 channels (dword),
// fp32 accumulate, unroll 4 edges, write bf16x2 once. 256 B/row reads.
// ---------------------------------------------------------------------------
__global__ __launch_bounds__(256) void gather_kernel(const ushort* __restrict__ hd,
                                                     const int* __restrict__ rowPtr,
                                                     const int* __restrict__ csrSrc,
                                                     ushort* __restrict__ agg, int N) {
  int node = (blockIdx.x * 256 + threadIdx.x) >> 6;
  if (node >= N) return;
  int lane = threadIdx.x & 63;
  int cofs = lane * 2;
  int beg = __builtin_amdgcn_readfirstlane(rowPtr[node]);
  int end = __builtin_amdgcn_readfirstlane(rowPtr[node + 1]);
  float a0 = 0.f, a1 = 0.f, b0 = 0.f, b1 = 0.f;
  float c0 = 0.f, c1 = 0.f, d0 = 0.f, d1 = 0.f;
  int e = beg;
  for (; e + 3 < end; e += 4) {
    int s0 = __builtin_amdgcn_readfirstlane(csrSrc[e]);
    int s1 = __builtin_amdgcn_readfirstlane(csrSrc[e + 1]);
    int s2 = __builtin_amdgcn_readfirstlane(csrSrc[e + 2]);
    int s3 = __builtin_amdgcn_readfirstlane(csrSrc[e + 3]);
    unsigned v0 = *(const unsigned*)(hd + (size_t)s0 * C128 + cofs);
    unsigned v1 = *(const unsigned*)(hd + (size_t)s1 * C128 + cofs);
    unsigned v2 = *(const unsigned*)(hd + (size_t)s2 * C128 + cofs);
    unsigned v3 = *(const unsigned*)(hd + (size_t)s3 * C128 + cofs);
    a0 += bflo(v0); a1 += bfhi(v0);
    b0 += bflo(v1); b1 += bfhi(v1);
    c0 += bflo(v2); c1 += bfhi(v2);
    d0 += bflo(v3); d1 += bfhi(v3);
  }
  for (; e < end; ++e) {
    int s0 = __builtin_amdgcn_readfirstlane(csrSrc[e]);
    unsigned v0 = *(const unsigned*)(hd + (size_t)s0 * C128 + cofs);
    a0 += bflo(v0); a1 += bfhi(v0);
  }
  float rx = (a0 + b0) + (c0 + d0);
  float ry = (a1 + b1) + (c1 + d1);
  unsigned pack = (unsigned)f2bf(rx) | ((unsigned)f2bf(ry) << 16);
  *(unsigned*)(agg + (size_t)node * C128 + cofs) = pack;
}

// ---------------------------------------------------------------------------
// MFMA dual GEMM + fused epilogue.
// out[n,o] = sum_k agg[n,k]Wrel[o,k] + sum_k hd[n,k]Wroot[o,k] + b[o]
// Block: 256 thr (4 waves), tile 128 nodes x 128 outs, K=256 in 8 chunks of 32.
// A staged in LDS (pad 36: 16 lanes -> 16 distinct banks); W-frags read direct
// from global (64 KB total, L2-resident). mfma_f32_16x16x32_bf16, acc fp32.
// mode=1: ReLU + next-layer dropout, write bf16. mode=0: write fp32 (d_out).
// ---------------------------------------------------------------------------
__global__ __launch_bounds__(256) void gemm_kernel(const ushort* __restrict__ agg,
                                                   const ushort* __restrict__ hd,
                                                   const ushort* __restrict__ Wrel,
                                                   const ushort* __restrict__ Wroot,
                                                   const float* __restrict__ bias,
                                                   const void* __restrict__ mask,
                                                   const int* __restrict__ flags,
                                                   void* __restrict__ outp,
                                                   int mode, int N) {
  __shared__ ushort As[128][36];

  const int tid = threadIdx.x;
  const int wave = tid >> 6, lane = tid & 63;
  const int quad = lane >> 4, l16 = lane & 15;
  const int node0 = blockIdx.x * 128;

  f32x4 acc[2][8];
#pragma unroll
  for (int mt = 0; mt < 2; ++mt)
#pragma unroll
    for (int nt = 0; nt < 8; ++nt) acc[mt][nt] = (f32x4)0.f;

  float bv[8];
#pragma unroll
  for (int nt = 0; nt < 8; ++nt) bv[nt] = bias[nt * 16 + l16];

  const int srow = tid >> 2;            // staging row 0..63 (+64 second half)
  const int scol = (tid & 3) * 8;       // staging col {0,8,16,24}

  for (int c = 0; c < 8; ++c) {
    const ushort* A = (c < 4) ? agg : hd;
    const ushort* W = (c < 4) ? Wrel : Wroot;
    const int k0 = (c & 3) * 32;

    // stage A chunk: 128 rows x 32 k (8 KB), 2x 16B loads per thread
#pragma unroll
    for (int h = 0; h < 2; ++h) {
      int row = srow + h * 64;
      int g = node0 + row;
      if (g >= N) g = N - 1;
      s16x8 v = *(const s16x8*)(A + (size_t)g * C128 + k0 + scol);
      *(ushort4*)&As[row][scol]     = ((ushort4*)&v)[0];
      *(ushort4*)&As[row][scol + 4] = ((ushort4*)&v)[1];
    }
    __syncthreads();

    // A fragments for this wave's two 16-row tiles
    s16x8 afr[2];
#pragma unroll
    for (int mt = 0; mt < 2; ++mt) {
      const ushort* p = &As[wave * 32 + mt * 16 + l16][quad * 8];
      union { ushort4 h[2]; s16x8 v; } u;
      u.h[0] = *(const ushort4*)p;
      u.h[1] = *(const ushort4*)(p + 4);
      afr[mt] = u.v;
    }

#pragma unroll
    for (int nt = 0; nt < 8; ++nt) {
      s16x8 bfr = *(const s16x8*)(W + (size_t)(nt * 16 + l16) * C128 + k0 + quad * 8);
      acc[0][nt] = __builtin_amdgcn_mfma_f32_16x16x32_bf16(afr[0], bfr, acc[0][nt], 0, 0, 0);
      acc[1][nt] = __builtin_amdgcn_mfma_f32_16x16x32_bf16(afr[1], bfr, acc[1][nt], 0, 0, 0);
    }
    __syncthreads();
  }

  // Epilogue. C/D layout: col = lane&15, row = quad*4 + reg.
  if (mode) {
    ushort* ob = (ushort*)outp;
    const int m32 = flags[1];
#pragma unroll
    for (int mt = 0; mt < 2; ++mt)
#pragma unroll
      for (int r = 0; r < 4; ++r) {
        int node = node0 + wave * 32 + mt * 16 + quad * 4 + r;
        if (node >= N) continue;
#pragma unroll
        for (int nt = 0; nt < 8; ++nt) {
          int o = nt * 16 + l16;
          float v = acc[mt][nt][r] + bv[nt];
          v = fmaxf(v, 0.f);
          int keep = m32 ? ((const int*)mask)[(size_t)node * C128 + o]
                         : (int)((const unsigned char*)mask)[(size_t)node * C128 + o];
          ob[(size_t)node * C128 + o] = keep ? f2bf(v * 2.5f) : (ushort)0;
        }
      }
  } else {
    float* of = (float*)outp;
#pragma unroll
    for (int mt = 0; mt < 2; ++mt)
#pragma unroll
      for (int r = 0; r < 4; ++r) {
        int node = node0 + wave * 32 + mt * 16 + quad * 4 + r;
        if (node >= N) continue;
#pragma unroll
        for (int nt = 0; nt < 8; ++nt) {
          int o = nt * 16 + l16;
          of[(size_t)node * C128 + o] = acc[mt][nt][r] + bv[nt];
        }
      }
  }
}

// ---------------------------------------------------------------------------
extern "C" void kernel_launch(void* const* d_in, const int* in_sizes, int n_in,
                              void* d_out, int out_size, void* d_ws, size_t ws_size,
                              hipStream_t stream) {
  const float* x      = (const float*)d_in[0];
  const int*   eidx   = (const int*)d_in[1];
  const float* Wrel0  = (const float*)d_in[2];
  const float* Wroot0 = (const float*)d_in[3];
  const float* b0     = (const float*)d_in[4];
  const float* Wrel1  = (const float*)d_in[5];
  const float* Wroot1 = (const float*)d_in[6];
  const float* b1     = (const float*)d_in[7];
  const float* Wrel2  = (const float*)d_in[8];
  const float* Wroot2 = (const float*)d_in[9];
  const float* b2     = (const float*)d_in[10];
  const void*  drop0  = d_in[11];
  const void*  drop1  = d_in[12];
  const void*  drop2  = d_in[13];

  const int N  = in_sizes[0] / C128;
  const int E  = in_sizes[1] / 2;
  const int NC = N * C128;
  const int nb = (N + 255) / 256;

  char*   ws     = (char*)d_ws;
  int*    flags  = (int*)ws;                          // 256 B
  ushort* Wb     = (ushort*)(ws + 256);               // 6*16384 bf16
  ushort* hdA    = Wb + 6 * 16384;
  ushort* hdB    = hdA + NC;
  ushort* agg    = hdB + NC;
  int*    deg    = (int*)(agg + NC);
  int*    rowPtr = deg + N;
  int*    cur    = rowPtr + N + 1;
  int*    csrSrc = cur + N;
  int*    bsums  = csrSrc + E;

  const ushort* Wr0 = Wb;
  const ushort* Wt0 = Wb + 16384;
  const ushort* Wr1 = Wb + 2 * 16384;
  const ushort* Wt1 = Wb + 3 * 16384;
  const ushort* Wr2 = Wb + 4 * 16384;
  const ushort* Wt2 = Wb + 5 * 16384;

  detect_kernel<<<1, 64, 0, stream>>>(eidx, (const int*)drop0, flags);
  wconv_kernel<<<(6 * 16384 + 255) / 256, 256, 0, stream>>>(Wrel0, Wroot0, Wrel1,
                                                            Wroot1, Wrel2, Wroot2, Wb);

  // CSR build (once)
  hipMemsetAsync(deg, 0, (size_t)N * sizeof(int), stream);
  hist_kernel<<<(E + 255) / 256, 256, 0, stream>>>(eidx, flags, deg, E);
  scan1_kernel<<<nb, 256, 0, stream>>>(deg, bsums, N);
  scan2_kernel<<<1, 64, 0, stream>>>(bsums, nb);
  scan3_kernel<<<nb, 256, 0, stream>>>(deg, bsums, rowPtr, cur, N);
  fill_kernel<<<(E + 255) / 256, 256, 0, stream>>>(eidx, flags, cur, csrSrc, E);

  const int n4 = NC / 4;
  const int dropGrid = (n4 + 255) / 256;
  const int gathGrid = (N + 3) / 4;
  const int gemmGrid = (N + 127) / 128;

  // layer 0: x -> hdA -> agg -> hdB (relu + drop1 fused)
  drop_in_kernel<<<dropGrid, 256, 0, stream>>>(x, drop0, flags, hdA, n4);
  gather_kernel<<<gathGrid, 256, 0, stream>>>(hdA, rowPtr, csrSrc, agg, N);
  gemm_kernel<<<gemmGrid, 256, 0, stream>>>(agg, hdA, Wr0, Wt0, b0, drop1, flags,
                                            hdB, 1, N);
  // layer 1: hdB -> agg -> hdA (relu + drop2 fused)
  gather_kernel<<<gathGrid, 256, 0, stream>>>(hdB, rowPtr, csrSrc, agg, N);
  gemm_kernel<<<gemmGrid, 256, 0, stream>>>(agg, hdB, Wr1, Wt1, b1, drop2, flags,
                                            hdA, 1, N);
  // layer 2: hdA -> agg -> d_out (fp32, no relu/mask)
  gather_kernel<<<gathGrid, 256, 0, stream>>>(hdA, rowPtr, csrSrc, agg, N);
  gemm_kernel<<<gemmGrid, 256, 0, stream>>>(agg, hdA, Wr2, Wt2, b2, nullptr, flags,
                                            d_out, 0, N);
}

// Round 4
// 416.723 us; speedup vs baseline: 10.5940x; 1.1429x over previous
//
#include <hip/hip_runtime.h>

// GraphConv x3 on MI355X. R4: barrier-free direct-global MFMA GEMM (A rows are
// wave-private -> no LDS staging), W pre-packed into MFMA fragment order
// (1KB coalesced L2-hot B-frag loads), gather with 4 edges/wave x 16B loads,
// parallel scan2, fused prep kernel.

#define C128 128

typedef short s16x8 __attribute__((ext_vector_type(8)));
typedef float f32x4 __attribute__((ext_vector_type(4)));

__device__ __forceinline__ ushort f2bf(float f) {        // RNE fp32->bf16
  unsigned u = __builtin_bit_cast(unsigned, f);
  u = (u + 0x7FFFu + ((u >> 16) & 1u)) >> 16;
  return (ushort)u;
}
__device__ __forceinline__ float bflo(unsigned v) {
  return __builtin_bit_cast(float, v << 16);
}
__device__ __forceinline__ float bfhi(unsigned v) {
  return __builtin_bit_cast(float, v & 0xFFFF0000u);
}
__device__ __forceinline__ unsigned pack2(float lo, float hi) {
  return (unsigned)f2bf(lo) | ((unsigned)f2bf(hi) << 16);
}

// ---------------------------------------------------------------------------
// prep: detect dtypes (flags), zero deg[], pack 6 weight mats into MFMA
// fragment order. Wpack layout per layer L (32768 ushorts):
//   idx = (c*8+nt)*512 + lane*8 + j ; c<4 -> Wrel chunk c, c>=4 -> Wroot c-4
//   value = W[o=nt*16+(lane&15)][k=(c&3)*32+(lane>>4)*8+j]
// ---------------------------------------------------------------------------
__global__ __launch_bounds__(256) void prep_kernel(const float* __restrict__ Wr0,
                                                   const float* __restrict__ Wt0,
                                                   const float* __restrict__ Wr1,
                                                   const float* __restrict__ Wt1,
                                                   const float* __restrict__ Wr2,
                                                   const float* __restrict__ Wt2,
                                                   ushort* __restrict__ Wpack,
                                                   const int* __restrict__ eidx,
                                                   const int* __restrict__ mask,
                                                   int* __restrict__ flags,
                                                   int* __restrict__ deg,
                                                   int N, int E) {
  int t = blockIdx.x * 256 + threadIdx.x;
  if (blockIdx.x == 0 && threadIdx.x == 0) {
    int e64 = 1;
    for (int i = 0; i < 64; ++i)
      if (eidx[2 * i + 1] != 0) { e64 = 0; break; }
    int m32 = 1;
    for (int i = 0; i < 64; ++i)
      if ((unsigned)mask[i] > 1u) { m32 = 0; break; }
    flags[0] = e64;
    flags[1] = m32;
  }
  if (t < N) deg[t] = 0;
  if (t < 3 * 32768) {
    int L = t >> 15;
    int r = t & 32767;
    int c = r >> 12;
    int nt = (r >> 9) & 7;
    int lane = (r >> 3) & 63;
    int j = r & 7;
    int o = nt * 16 + (lane & 15);
    int k = (c & 3) * 32 + (lane >> 4) * 8 + j;
    const float* src;
    if (L == 0)      src = (c < 4) ? Wr0 : Wt0;
    else if (L == 1) src = (c < 4) ? Wr1 : Wt1;
    else             src = (c < 4) ? Wr2 : Wt2;
    Wpack[t] = f2bf(src[o * C128 + k]);
  }
}

// ---------------------------------------------------------------------------
// CSR build
// ---------------------------------------------------------------------------
__global__ __launch_bounds__(256) void hist_kernel(const int* __restrict__ eidx,
                                                   const int* __restrict__ flags,
                                                   int* __restrict__ deg, int E) {
  int e = blockIdx.x * 256 + threadIdx.x;
  if (e >= E) return;
  int dst = flags[0] ? eidx[2 * E + 2 * e] : eidx[E + e];
  atomicAdd(&deg[dst], 1);
}

__global__ __launch_bounds__(256) void scan1_kernel(const int* __restrict__ deg,
                                                    int* __restrict__ blockSums, int N) {
  __shared__ int s[256];
  int i = blockIdx.x * 256 + threadIdx.x;
  s[threadIdx.x] = (i < N) ? deg[i] : 0;
  __syncthreads();
  for (int off = 128; off > 0; off >>= 1) {
    if (threadIdx.x < off) s[threadIdx.x] += s[threadIdx.x + off];
    __syncthreads();
  }
  if (threadIdx.x == 0) blockSums[blockIdx.x] = s[0];
}

// parallel exclusive scan over <=256 block sums (was serial 196-iter loop)
__global__ __launch_bounds__(256) void scan2_kernel(int* __restrict__ blockSums, int nb) {
  __shared__ int s[256];
  int t = threadIdx.x;
  int v = (t < nb) ? blockSums[t] : 0;
  s[t] = v;
  __syncthreads();
  for (int off = 1; off < 256; off <<= 1) {
    int u = (t >= off) ? s[t - off] : 0;
    __syncthreads();
    s[t] += u;
    __syncthreads();
  }
  if (t < nb) blockSums[t] = s[t] - v;
}

__global__ __launch_bounds__(256) void scan3_kernel(const int* __restrict__ deg,
                                                    const int* __restrict__ blockSums,
                                                    int* __restrict__ rowPtr,
                                                    int* __restrict__ cur, int N) {
  __shared__ int s[256];
  int i = blockIdx.x * 256 + threadIdx.x;
  int v = (i < N) ? deg[i] : 0;
  s[threadIdx.x] = v;
  __syncthreads();
  for (int off = 1; off < 256; off <<= 1) {
    int t = (threadIdx.x >= (unsigned)off) ? s[threadIdx.x - off] : 0;
    __syncthreads();
    s[threadIdx.x] += t;
    __syncthreads();
  }
  int excl = s[threadIdx.x] - v + blockSums[blockIdx.x];
  if (i < N) {
    rowPtr[i] = excl;
    cur[i] = excl;
    if (i == N - 1) rowPtr[N] = excl + v;
  }
}

__global__ __launch_bounds__(256) void fill_kernel(const int* __restrict__ eidx,
                                                   const int* __restrict__ flags,
                                                   int* __restrict__ cur,
                                                   int* __restrict__ csrSrc, int E) {
  int e = blockIdx.x * 256 + threadIdx.x;
  if (e >= E) return;
  int src, dst;
  if (flags[0]) { src = eidx[2 * e]; dst = eidx[2 * E + 2 * e]; }
  else          { src = eidx[e];     dst = eidx[E + e]; }
  int pos = atomicAdd(&cur[dst], 1);
  csrSrc[pos] = src;
}

// ---------------------------------------------------------------------------
// Input dropout: fp32 x -> bf16 hd
// ---------------------------------------------------------------------------
__global__ __launch_bounds__(256) void drop_in_kernel(const float* __restrict__ x,
                                                      const void* __restrict__ mask,
                                                      const int* __restrict__ flags,
                                                      ushort* __restrict__ out, int n4) {
  int i = blockIdx.x * 256 + threadIdx.x;
  if (i >= n4) return;
  float4 v = ((const float4*)x)[i];
  int k0, k1, k2, k3;
  if (flags[1]) {
    int4 m = ((const int4*)mask)[i];
    k0 = m.x; k1 = m.y; k2 = m.z; k3 = m.w;
  } else {
    uchar4 m = ((const uchar4*)mask)[i];
    k0 = m.x; k1 = m.y; k2 = m.z; k3 = m.w;
  }
  ushort4 r;
  r.x = k0 ? f2bf(v.x * 2.5f) : (ushort)0;
  r.y = k1 ? f2bf(v.y * 2.5f) : (ushort)0;
  r.z = k2 ? f2bf(v.z * 2.5f) : (ushort)0;
  r.w = k3 ? f2bf(v.w * 2.5f) : (ushort)0;
  ((ushort4*)out)[i] = r;
}

// ---------------------------------------------------------------------------
// Gather: one wave per dst node. 4 edge-subgroups x 16 lanes x 8 channels
// (16B loads), 2 edges in flight per lane per iter, xor-shuffle reduce.
// ---------------------------------------------------------------------------
__global__ __launch_bounds__(256) void gather_kernel(const ushort* __restrict__ hd,
                                                     const int* __restrict__ rowPtr,
                                                     const int* __restrict__ csrSrc,
                                                     ushort* __restrict__ agg, int N) {
  int node = (blockIdx.x * 256 + threadIdx.x) >> 6;
  if (node >= N) return;
  int lane = threadIdx.x & 63;
  int grp = lane >> 4, l16 = lane & 15;
  int cofs = l16 * 8;
  int beg = __builtin_amdgcn_readfirstlane(rowPtr[node]);
  int end = __builtin_amdgcn_readfirstlane(rowPtr[node + 1]);
  float a[8] = {0.f, 0.f, 0.f, 0.f, 0.f, 0.f, 0.f, 0.f};
  float b[8] = {0.f, 0.f, 0.f, 0.f, 0.f, 0.f, 0.f, 0.f};
  const ushort* base = hd + cofs;
  for (int e = beg + grp; e < end; e += 8) {
    {
      int s = csrSrc[e];
      uint4 v = *(const uint4*)(base + (size_t)s * C128);
      a[0] += bflo(v.x); a[1] += bfhi(v.x);
      a[2] += bflo(v.y); a[3] += bfhi(v.y);
      a[4] += bflo(v.z); a[5] += bfhi(v.z);
      a[6] += bflo(v.w); a[7] += bfhi(v.w);
    }
    int e1 = e + 4;
    if (e1 < end) {
      int s = csrSrc[e1];
      uint4 v = *(const uint4*)(base + (size_t)s * C128);
      b[0] += bflo(v.x); b[1] += bfhi(v.x);
      b[2] += bflo(v.y); b[3] += bfhi(v.y);
      b[4] += bflo(v.z); b[5] += bfhi(v.z);
      b[6] += bflo(v.w); b[7] += bfhi(v.w);
    }
  }
#pragma unroll
  for (int i = 0; i < 8; ++i) {
    float v = a[i] + b[i];
    v += __shfl_xor(v, 16, 64);
    v += __shfl_xor(v, 32, 64);
    a[i] = v;
  }
  if (grp == 0) {
    uint4 p;
    p.x = pack2(a[0], a[1]);
    p.y = pack2(a[2], a[3]);
    p.z = pack2(a[4], a[5]);
    p.w = pack2(a[6], a[7]);
    *(uint4*)(agg + (size_t)node * C128 + cofs) = p;
  }
}

// ---------------------------------------------------------------------------
// Barrier-free MFMA dual GEMM + fused epilogue.
// One wave = 16 rows x 128 cols, K=256 ([agg|hd]). A frags direct from global
// (each byte read once); B frags from pre-packed Wpack (1KB coalesced, L2-hot).
// Full 8x8 unroll, no LDS, no __syncthreads. N must be a multiple of 16.
// mode=1: ReLU + next-layer dropout -> bf16. mode=0: +bias -> fp32 (d_out).
// ---------------------------------------------------------------------------
__global__ __launch_bounds__(256, 3) void gemm_kernel(const ushort* __restrict__ agg,
                                                      const ushort* __restrict__ hd,
                                                      const ushort* __restrict__ Wpack,
                                                      const float* __restrict__ bias,
                                                      const void* __restrict__ mask,
                                                      const int* __restrict__ flags,
                                                      void* __restrict__ outp,
                                                      int mode, int N) {
  int gw = (blockIdx.x * 256 + threadIdx.x) >> 6;
  int row0 = gw << 4;
  if (row0 >= N) return;
  int lane = threadIdx.x & 63;
  int quad = lane >> 4, l16 = lane & 15;

  f32x4 acc[8];
#pragma unroll
  for (int nt = 0; nt < 8; ++nt) acc[nt] = (f32x4)0.f;

  float bv[8];
#pragma unroll
  for (int nt = 0; nt < 8; ++nt) bv[nt] = bias[nt * 16 + l16];

  const ushort* Ar_agg = agg + (size_t)(row0 + l16) * C128 + quad * 8;
  const ushort* Ar_hd  = hd  + (size_t)(row0 + l16) * C128 + quad * 8;
  const ushort* wp = Wpack + lane * 8;

#pragma unroll
  for (int c = 0; c < 8; ++c) {
    const ushort* Ar = (c < 4) ? Ar_agg : Ar_hd;
    s16x8 afr = *(const s16x8*)(Ar + (c & 3) * 32);
#pragma unroll
    for (int nt = 0; nt < 8; ++nt) {
      s16x8 bfr = *(const s16x8*)(wp + (c * 8 + nt) * 512);
      acc[nt] = __builtin_amdgcn_mfma_f32_16x16x32_bf16(afr, bfr, acc[nt], 0, 0, 0);
    }
  }

  // Epilogue. C/D layout: col = lane&15, row = quad*4 + reg.
  if (mode) {
    ushort* ob = (ushort*)outp;
    const int m32 = flags[1];
#pragma unroll
    for (int r = 0; r < 4; ++r) {
      size_t rb = (size_t)(row0 + quad * 4 + r) * C128;
#pragma unroll
      for (int nt = 0; nt < 8; ++nt) {
        int o = nt * 16 + l16;
        float v = fmaxf(acc[nt][r] + bv[nt], 0.f);
        int keep = m32 ? ((const int*)mask)[rb + o]
                       : (int)((const unsigned char*)mask)[rb + o];
        ob[rb + o] = keep ? f2bf(v * 2.5f) : (ushort)0;
      }
    }
  } else {
    float* of = (float*)outp;
#pragma unroll
    for (int r = 0; r < 4; ++r) {
      size_t rb = (size_t)(row0 + quad * 4 + r) * C128;
#pragma unroll
      for (int nt = 0; nt < 8; ++nt)
        of[rb + nt * 16 + l16] = acc[nt][r] + bv[nt];
    }
  }
}

// ---------------------------------------------------------------------------
extern "C" void kernel_launch(void* const* d_in, const int* in_sizes, int n_in,
                              void* d_out, int out_size, void* d_ws, size_t ws_size,
                              hipStream_t stream) {
  const float* x      = (const float*)d_in[0];
  const int*   eidx   = (const int*)d_in[1];
  const float* Wrel0  = (const float*)d_in[2];
  const float* Wroot0 = (const float*)d_in[3];
  const float* b0     = (const float*)d_in[4];
  const float* Wrel1  = (const float*)d_in[5];
  const float* Wroot1 = (const float*)d_in[6];
  const float* b1     = (const float*)d_in[7];
  const float* Wrel2  = (const float*)d_in[8];
  const float* Wroot2 = (const float*)d_in[9];
  const float* b2     = (const float*)d_in[10];
  const void*  drop0  = d_in[11];
  const void*  drop1  = d_in[12];
  const void*  drop2  = d_in[13];

  const int N  = in_sizes[0] / C128;
  const int E  = in_sizes[1] / 2;
  const int NC = N * C128;
  const int nb = (N + 255) / 256;

  char*   ws     = (char*)d_ws;
  int*    flags  = (int*)ws;                         // 256 B
  ushort* Wpack  = (ushort*)(ws + 256);              // 3*32768 bf16
  ushort* hdA    = Wpack + 3 * 32768;
  ushort* hdB    = hdA + NC;
  ushort* agg    = hdB + NC;
  int*    deg    = (int*)(agg + NC);
  int*    rowPtr = deg + N;
  int*    cur    = rowPtr + N + 1;
  int*    csrSrc = cur + N;
  int*    bsums  = csrSrc + E;

  const ushort* Wp0 = Wpack;
  const ushort* Wp1 = Wpack + 32768;
  const ushort* Wp2 = Wpack + 2 * 32768;

  prep_kernel<<<(3 * 32768 + 255) / 256, 256, 0, stream>>>(
      Wrel0, Wroot0, Wrel1, Wroot1, Wrel2, Wroot2, Wpack,
      eidx, (const int*)drop0, flags, deg, N, E);

  hist_kernel<<<(E + 255) / 256, 256, 0, stream>>>(eidx, flags, deg, E);
  scan1_kernel<<<nb, 256, 0, stream>>>(deg, bsums, N);
  scan2_kernel<<<1, 256, 0, stream>>>(bsums, nb);
  scan3_kernel<<<nb, 256, 0, stream>>>(deg, bsums, rowPtr, cur, N);
  fill_kernel<<<(E + 255) / 256, 256, 0, stream>>>(eidx, flags, cur, csrSrc, E);

  const int n4 = NC / 4;
  const int dropGrid = (n4 + 255) / 256;
  const int gathGrid = (N + 3) / 4;                  // 1 wave/node
  const int gemmGrid = (N / 16 + 3) / 4;             // 1 wave/16 rows

  drop_in_kernel<<<dropGrid, 256, 0, stream>>>(x, drop0, flags, hdA, n4);

  // layer 0: hdA -> agg -> hdB (relu + drop1 fused)
  gather_kernel<<<gathGrid, 256, 0, stream>>>(hdA, rowPtr, csrSrc, agg, N);
  gemm_kernel<<<gemmGrid, 256, 0, stream>>>(agg, hdA, Wp0, b0, drop1, flags, hdB, 1, N);
  // layer 1: hdB -> agg -> hdA (relu + drop2 fused)
  gather_kernel<<<gathGrid, 256, 0, stream>>>(hdB, rowPtr, csrSrc, agg, N);
  gemm_kernel<<<gemmGrid, 256, 0, stream>>>(agg, hdB, Wp1, b1, drop2, flags, hdA, 1, N);
  // layer 2: hdA -> agg -> d_out (fp32)
  gather_kernel<<<gathGrid, 256, 0, stream>>>(hdA, rowPtr, csrSrc, agg, N);
  gemm_kernel<<<gemmGrid, 256, 0, stream>>>(agg, hdA, Wp2, b2, nullptr, flags, d_out, 0, N);
}